// Round 8
// baseline (1120.198 us; speedup 1.0000x reference)
//
#include <hip/hip_runtime.h>
#include <cstdint>
#include <cstddef>

#define D_DIM 256
#define T_DIM 512
#define B_DIM 128
#define S_DIM 512

typedef __attribute__((ext_vector_type(8))) short short8;
typedef __attribute__((ext_vector_type(4))) float f32x4;

// ---------- helpers ----------
__device__ inline unsigned short f2bf(float x) {
    unsigned u = __builtin_bit_cast(unsigned, x);
    unsigned r = (u + 0x7fffu + ((u >> 16) & 1u)) >> 16;
    return (unsigned short)r;
}
__device__ inline float bf2f(unsigned short b) {
    unsigned u = ((unsigned)b) << 16;
    return __builtin_bit_cast(float, u);
}
__device__ inline float fast_tanh(float x) {
    float ax = __builtin_fabsf(x);
    float e  = __expf(-2.0f * ax);
    float r  = (1.0f - e) * __builtin_amdgcn_rcpf(1.0f + e);
    return __builtin_copysignf(r, x);
}
// Truncation split (head GEMM's on-the-fly B path only).
__device__ inline void split4(float4 v, uint2& hi, uint2& lo) {
    unsigned u0 = __builtin_bit_cast(unsigned, v.x);
    unsigned u1 = __builtin_bit_cast(unsigned, v.y);
    unsigned u2 = __builtin_bit_cast(unsigned, v.z);
    unsigned u3 = __builtin_bit_cast(unsigned, v.w);
    hi.x = (u0 >> 16) | (u1 & 0xFFFF0000u);
    hi.y = (u2 >> 16) | (u3 & 0xFFFF0000u);
    float r0 = v.x - __builtin_bit_cast(float, u0 & 0xFFFF0000u);
    float r1 = v.y - __builtin_bit_cast(float, u1 & 0xFFFF0000u);
    float r2 = v.z - __builtin_bit_cast(float, u2 & 0xFFFF0000u);
    float r3 = v.w - __builtin_bit_cast(float, u3 & 0xFFFF0000u);
    lo.x = (__builtin_bit_cast(unsigned, r0) >> 16)
         | (__builtin_bit_cast(unsigned, r1) & 0xFFFF0000u);
    lo.y = (__builtin_bit_cast(unsigned, r2) >> 16)
         | (__builtin_bit_cast(unsigned, r3) & 0xFFFF0000u);
}

// ---------- split_planes: fp32 array -> bf16 hi/lo planes (RNE) ----------
// R7: v3 GEMMs re-split identical data on every staging pass (weights 512x!)
// -> staging-VALU-bound (~192 VALU/thread/iter).  Split ONCE here.
__global__ void split_planes(const float* __restrict__ src,
                             unsigned short* __restrict__ hi,
                             unsigned short* __restrict__ lo, int n4)
{
    int i = blockIdx.x * blockDim.x + threadIdx.x;
    if (i >= n4) return;
    float4 v = ((const float4*)src)[i];
    unsigned h0 = f2bf(v.x), h1 = f2bf(v.y), h2 = f2bf(v.z), h3 = f2bf(v.w);
    unsigned l0 = f2bf(v.x - bf2f((unsigned short)h0));
    unsigned l1 = f2bf(v.y - bf2f((unsigned short)h1));
    unsigned l2 = f2bf(v.z - bf2f((unsigned short)h2));
    unsigned l3 = f2bf(v.w - bf2f((unsigned short)h3));
    uint2 H, L;
    H.x = h0 | (h1 << 16); H.y = h2 | (h3 << 16);
    L.x = l0 | (l1 << 16); L.y = l2 | (l3 << 16);
    ((uint2*)hi)[i] = H;
    ((uint2*)lo)[i] = L;
}

// ---------- GEMM v4a: A planes x B planes (pre-split bf16), C = A@B^T ------
// Staging is pure 16B copies (no split VALU).  Tile/compute structure is the
// R4/R7-verified one: 128x128, BK=64, XOR swizzle ((r&7)<<4), A prefetched
// one iter ahead, B issued pre-barrier, 3 MFMA (hh+lh+hl) per pair.
__global__ __launch_bounds__(256, 2)
void gemm_pp(const unsigned short* __restrict__ Ahi, const unsigned short* __restrict__ Alo,
             const unsigned short* __restrict__ Bhi, const unsigned short* __restrict__ Blo,
             float* __restrict__ C,
             const float* __restrict__ bias1, const float* __restrict__ bias2,
             const int* __restrict__ ids, int M, int N, int K)
{
    __shared__ char smem[65536];   // Ahi@0 Alo@16K Bhi@32K Blo@48K

    const int tid  = threadIdx.x;
    const int lane = tid & 63;
    const int quad = lane >> 4;
    const int lcol = lane & 15;
    const int wv   = tid >> 6;
    const int wm   = (wv & 1) * 64;
    const int wn   = (wv >> 1) * 64;
    const int m0   = blockIdx.x * 128;
    const int n0   = blockIdx.y * 128;

    // staging map: granule gid = tid + 256j -> row r = gid>>3 (0..127),
    // 16B granule g = gid&7 within the 128B bf16 row.
    const int r0 = tid >> 3;
    const int g  = tid & 7;
    const unsigned short* aHiP[4];
    const unsigned short* aLoP[4];
    const unsigned short* bHiP[4];
    const unsigned short* bLoP[4];
    int wof[4];
#pragma unroll
    for (int j = 0; j < 4; ++j) {
        int r = r0 + 32 * j;
        int am = ids ? ids[m0 + r] : (m0 + r);
        aHiP[j] = Ahi + (size_t)am * K + g * 8;
        aLoP[j] = Alo + (size_t)am * K + g * 8;
        bHiP[j] = Bhi + (size_t)(n0 + r) * K + g * 8;
        bLoP[j] = Blo + (size_t)(n0 + r) * K + g * 8;
        wof[j]  = (r * 128 + g * 16) ^ ((r & 7) << 4);
    }

    f32x4 acc[4][4];
#pragma unroll
    for (int mt = 0; mt < 4; ++mt)
#pragma unroll
        for (int nt = 0; nt < 4; ++nt) acc[mt][nt] = (f32x4){0.f, 0.f, 0.f, 0.f};

    const int nIt = K >> 6;
    short8 paH[4], paL[4];
#pragma unroll
    for (int j = 0; j < 4; ++j) {
        paH[j] = *(const short8*)(aHiP[j]);
        paL[j] = *(const short8*)(aLoP[j]);
    }

    for (int it = 0; it < nIt; ++it) {
        const int kc = it * 64;
        short8 pbH[4], pbL[4];
#pragma unroll
        for (int j = 0; j < 4; ++j) {
            pbH[j] = *(const short8*)(bHiP[j] + kc);
            pbL[j] = *(const short8*)(bLoP[j] + kc);
        }
        if (it) __syncthreads();
#pragma unroll
        for (int j = 0; j < 4; ++j) {
            *(short8*)(smem + 0     + wof[j]) = paH[j];
            *(short8*)(smem + 16384 + wof[j]) = paL[j];
        }
#pragma unroll
        for (int j = 0; j < 4; ++j) {
            *(short8*)(smem + 32768 + wof[j]) = pbH[j];
            *(short8*)(smem + 49152 + wof[j]) = pbL[j];
        }
        __syncthreads();
        if (it + 1 < nIt) {
#pragma unroll
            for (int j = 0; j < 4; ++j) {
                paH[j] = *(const short8*)(aHiP[j] + kc + 64);
                paL[j] = *(const short8*)(aLoP[j] + kc + 64);
            }
        }
#pragma unroll
        for (int ks = 0; ks < 2; ++ks) {
            short8 aHi[4], aLo[4], bHi[4], bLo[4];
#pragma unroll
            for (int mt = 0; mt < 4; ++mt) {
                int m = wm + mt * 16 + lcol;
                int off = (m * 128 + ks * 64 + quad * 16) ^ ((m & 7) << 4);
                aHi[mt] = *(const short8*)(smem + off);
                aLo[mt] = *(const short8*)(smem + 16384 + off);
            }
#pragma unroll
            for (int nt = 0; nt < 4; ++nt) {
                int n = wn + nt * 16 + lcol;
                int off = (n * 128 + ks * 64 + quad * 16) ^ ((n & 7) << 4);
                bHi[nt] = *(const short8*)(smem + 32768 + off);
                bLo[nt] = *(const short8*)(smem + 49152 + off);
            }
#pragma unroll
            for (int mt = 0; mt < 4; ++mt)
#pragma unroll
                for (int nt = 0; nt < 4; ++nt) {
                    acc[mt][nt] = __builtin_amdgcn_mfma_f32_16x16x32_bf16(aHi[mt], bHi[nt], acc[mt][nt], 0, 0, 0);
                    acc[mt][nt] = __builtin_amdgcn_mfma_f32_16x16x32_bf16(aLo[mt], bHi[nt], acc[mt][nt], 0, 0, 0);
                    acc[mt][nt] = __builtin_amdgcn_mfma_f32_16x16x32_bf16(aHi[mt], bLo[nt], acc[mt][nt], 0, 0, 0);
                }
        }
    }

    float bv[4];
#pragma unroll
    for (int nt = 0; nt < 4; ++nt) {
        int gn = n0 + wn + nt * 16 + lcol;
        float v = 0.f;
        if (bias1) v += bias1[gn];
        if (bias2) v += bias2[gn];
        bv[nt] = v;
    }
#pragma unroll
    for (int mt = 0; mt < 4; ++mt) {
        int gmb = m0 + wm + mt * 16 + quad * 4;
#pragma unroll
        for (int r = 0; r < 4; ++r) {
            float* crow = C + (size_t)(gmb + r) * N + n0 + wn;
#pragma unroll
            for (int nt = 0; nt < 4; ++nt)
                crow[nt * 16 + lcol] = acc[mt][nt][r] + bv[nt];
        }
    }
}

// ---------- GEMM v4b: A planes x B fp32 (on-the-fly split) -- head ---------
__global__ __launch_bounds__(256, 2)
void gemm_pf(const unsigned short* __restrict__ Ahi, const unsigned short* __restrict__ Alo,
             const float* __restrict__ Bf,
             float* __restrict__ C, int M, int N, int K)
{
    __shared__ char smem[65536];

    const int tid  = threadIdx.x;
    const int lane = tid & 63;
    const int quad = lane >> 4;
    const int lcol = lane & 15;
    const int wv   = tid >> 6;
    const int wm   = (wv & 1) * 64;
    const int wn   = (wv >> 1) * 64;
    const int m0   = blockIdx.x * 128;
    const int n0   = blockIdx.y * 128;

    // A: plane-granule map (as gemm_pp)
    const int r0 = tid >> 3;
    const int g  = tid & 7;
    const unsigned short* aHiP[4];
    const unsigned short* aLoP[4];
    int wofA[4];
#pragma unroll
    for (int j = 0; j < 4; ++j) {
        int r = r0 + 32 * j;
        aHiP[j] = Ahi + (size_t)(m0 + r) * K + g * 8;
        aLoP[j] = Alo + (size_t)(m0 + r) * K + g * 8;
        wofA[j] = (r * 128 + g * 16) ^ ((r & 7) << 4);
    }
    // B: fp32 rows, v3-verified split-staging map
    const int rm = tid >> 4;
    const int kq = tid & 15;
    const float* browp[8];
    int wofB[8];
#pragma unroll
    for (int i = 0; i < 8; ++i) {
        int r = rm + i * 16;
        browp[i] = Bf + (size_t)(n0 + r) * K;
        wofB[i]  = (r * 128 + kq * 8) ^ ((r & 7) << 4);
    }

    f32x4 acc[4][4];
#pragma unroll
    for (int mt = 0; mt < 4; ++mt)
#pragma unroll
        for (int nt = 0; nt < 4; ++nt) acc[mt][nt] = (f32x4){0.f, 0.f, 0.f, 0.f};

    const int nIt = K >> 6;
    short8 paH[4], paL[4];
#pragma unroll
    for (int j = 0; j < 4; ++j) {
        paH[j] = *(const short8*)(aHiP[j]);
        paL[j] = *(const short8*)(aLoP[j]);
    }

    for (int it = 0; it < nIt; ++it) {
        const int kc = it * 64;
        float4 pb[8];
#pragma unroll
        for (int i = 0; i < 8; ++i)
            pb[i] = *(const float4*)(browp[i] + kc + kq * 4);
        if (it) __syncthreads();
#pragma unroll
        for (int j = 0; j < 4; ++j) {
            *(short8*)(smem + 0     + wofA[j]) = paH[j];
            *(short8*)(smem + 16384 + wofA[j]) = paL[j];
        }
#pragma unroll
        for (int i = 0; i < 8; ++i) {
            uint2 hi, lo;
            split4(pb[i], hi, lo);
            *(uint2*)(smem + 32768 + wofB[i]) = hi;
            *(uint2*)(smem + 49152 + wofB[i]) = lo;
        }
        __syncthreads();
        if (it + 1 < nIt) {
#pragma unroll
            for (int j = 0; j < 4; ++j) {
                paH[j] = *(const short8*)(aHiP[j] + kc + 64);
                paL[j] = *(const short8*)(aLoP[j] + kc + 64);
            }
        }
#pragma unroll
        for (int ks = 0; ks < 2; ++ks) {
            short8 aHi[4], aLo[4], bHi[4], bLo[4];
#pragma unroll
            for (int mt = 0; mt < 4; ++mt) {
                int m = wm + mt * 16 + lcol;
                int off = (m * 128 + ks * 64 + quad * 16) ^ ((m & 7) << 4);
                aHi[mt] = *(const short8*)(smem + off);
                aLo[mt] = *(const short8*)(smem + 16384 + off);
            }
#pragma unroll
            for (int nt = 0; nt < 4; ++nt) {
                int n = wn + nt * 16 + lcol;
                int off = (n * 128 + ks * 64 + quad * 16) ^ ((n & 7) << 4);
                bHi[nt] = *(const short8*)(smem + 32768 + off);
                bLo[nt] = *(const short8*)(smem + 49152 + off);
            }
#pragma unroll
            for (int mt = 0; mt < 4; ++mt)
#pragma unroll
                for (int nt = 0; nt < 4; ++nt) {
                    acc[mt][nt] = __builtin_amdgcn_mfma_f32_16x16x32_bf16(aHi[mt], bHi[nt], acc[mt][nt], 0, 0, 0);
                    acc[mt][nt] = __builtin_amdgcn_mfma_f32_16x16x32_bf16(aLo[mt], bHi[nt], acc[mt][nt], 0, 0, 0);
                    acc[mt][nt] = __builtin_amdgcn_mfma_f32_16x16x32_bf16(aHi[mt], bLo[nt], acc[mt][nt], 0, 0, 0);
                }
        }
    }

#pragma unroll
    for (int mt = 0; mt < 4; ++mt) {
        int gmb = m0 + wm + mt * 16 + quad * 4;
#pragma unroll
        for (int r = 0; r < 4; ++r) {
            float* crow = C + (size_t)(gmb + r) * N + n0 + wn;
#pragma unroll
            for (int nt = 0; nt < 4; ++nt)
                crow[nt * 16 + lcol] = acc[mt][nt][r];
        }
    }
}

// LDS-only barrier (R1: neutral vs __syncthreads; kept, documents intent).
__device__ inline void lds_barrier() {
    asm volatile("s_waitcnt lgkmcnt(0)" ::: "memory");
    __builtin_amdgcn_s_barrier();
    __builtin_amdgcn_sched_barrier(0);
}

// ---------- MFMA Elman scan (R3 structure; output = bf16 hi/lo planes) -----
// hh and lh share B=wh: h_hi in A-row 0, h_lo in A-row 1 -> one MFMA gives
// hh (C reg[0]) and lh (C reg[1]).  hl via B=wl on same packed A.  32
// MFMA/wave/step; 437 us measured.  R7 change: emit h as bf16 hi/lo planes
// (already computed for LDS) so downstream GEMMs stage without splitting.
__global__ __launch_bounds__(512) __attribute__((amdgpu_waves_per_eu(2, 2)))
void rnn_scan_mfma(const float* __restrict__ pre, const float* __restrict__ Whh,
                   unsigned short* __restrict__ hHi, unsigned short* __restrict__ hLo)
{
    const int tid  = threadIdx.x;
    const int wave = tid >> 6;
    const int lane = tid & 63;
    const int quad = lane >> 4;
    const int lcol = lane & 15;
    const int b    = blockIdx.x;

    __shared__ short lds[1024];   // Hh[0]@0 Hl[0]@256 Hh[1]@512 Hl[1]@768
    for (int i = tid; i < 1024; i += 512) lds[i] = 0;

    short8 wh[2][8], wl[2][8];
#pragma unroll
    for (int tile = 0; tile < 2; ++tile) {
        const int n = wave * 32 + tile * 16 + lcol;
        const float* wr = Whh + (size_t)n * D_DIM + quad * 8;
#pragma unroll
        for (int kt = 0; kt < 8; ++kt) {
            float4 x0 = *(const float4*)(wr + kt * 32);
            float4 x1 = *(const float4*)(wr + kt * 32 + 4);
            float xs[8] = {x0.x, x0.y, x0.z, x0.w, x1.x, x1.y, x1.z, x1.w};
            short8 hi8, lo8;
#pragma unroll
            for (int j = 0; j < 8; ++j) {
                unsigned short h = f2bf(xs[j]);
                unsigned short l = f2bf(xs[j] - bf2f(h));
                hi8[j] = (short)h;
                lo8[j] = (short)l;
            }
            wh[tile][kt] = hi8;
            wl[tile][kt] = lo8;
        }
    }

    const bool active = (lane < 16);
    const int n0 = wave * 32 + lcol;
    const int n1 = n0 + 16;
    const size_t rowbase = (size_t)b * T_DIM * D_DIM;

    const short8 ZS = {0, 0, 0, 0, 0, 0, 0, 0};
    short8 aP[8];
#pragma unroll
    for (int kt = 0; kt < 8; ++kt) aP[kt] = ZS;

    const int aq = quad * 8;

    float pv0 = 0.f, pv1 = 0.f, nv0 = 0.f, nv1 = 0.f;
    if (active) {
        pv0 = pre[rowbase + n0];
        pv1 = pre[rowbase + n1];
        nv0 = pre[rowbase + D_DIM + n0];
        nv1 = pre[rowbase + D_DIM + n1];
    }
    lds_barrier();

    const f32x4 Z = {0.f, 0.f, 0.f, 0.f};

    for (int t = 0; t < T_DIM; ++t) {
        float qv0 = 0.f, qv1 = 0.f;
        if (active && t + 2 < T_DIM) {
            const float* p2 = pre + rowbase + (size_t)(t + 2) * D_DIM;
            qv0 = p2[n0];
            qv1 = p2[n1];
        }

        const int bh = (t & 1) ? 512 : 0;
        if (lcol < 2) {
            const short* pa = lds + bh + lcol * 256 + aq;
#pragma unroll
            for (int kt = 0; kt < 8; ++kt)
                aP[kt] = *(const short8*)(pa + kt * 32);
        }

        f32x4 a1t0, a1t1, a2t0, a2t1;
        a1t0 = __builtin_amdgcn_mfma_f32_16x16x32_bf16(aP[0], wh[0][0], Z, 0, 0, 0);
        a1t1 = __builtin_amdgcn_mfma_f32_16x16x32_bf16(aP[0], wh[1][0], Z, 0, 0, 0);
        a2t0 = __builtin_amdgcn_mfma_f32_16x16x32_bf16(aP[0], wl[0][0], Z, 0, 0, 0);
        a2t1 = __builtin_amdgcn_mfma_f32_16x16x32_bf16(aP[0], wl[1][0], Z, 0, 0, 0);
#pragma unroll
        for (int kt = 1; kt < 8; ++kt) {
            a1t0 = __builtin_amdgcn_mfma_f32_16x16x32_bf16(aP[kt], wh[0][kt], a1t0, 0, 0, 0);
            a1t1 = __builtin_amdgcn_mfma_f32_16x16x32_bf16(aP[kt], wh[1][kt], a1t1, 0, 0, 0);
            a2t0 = __builtin_amdgcn_mfma_f32_16x16x32_bf16(aP[kt], wl[0][kt], a2t0, 0, 0, 0);
            a2t1 = __builtin_amdgcn_mfma_f32_16x16x32_bf16(aP[kt], wl[1][kt], a2t1, 0, 0, 0);
        }

        if (active) {
            const int wH = (t & 1) ? 0 : 512;
            float x0 = a1t0[0] + a1t0[1] + a2t0[0] + pv0;
            float x1 = a1t1[0] + a1t1[1] + a2t1[0] + pv1;
            float h0 = fast_tanh(x0);
            float h1 = fast_tanh(x1);
            unsigned short h0h = f2bf(h0);
            unsigned short h0l = f2bf(h0 - bf2f(h0h));
            unsigned short h1h = f2bf(h1);
            unsigned short h1l = f2bf(h1 - bf2f(h1h));
            const size_t hb = rowbase + (size_t)t * D_DIM;
            hHi[hb + n0] = h0h;            // stays in flight across steps
            hLo[hb + n0] = h0l;
            hHi[hb + n1] = h1h;
            hLo[hb + n1] = h1l;
            lds[wH + n0]       = (short)h0h;
            lds[wH + n1]       = (short)h1h;
            lds[wH + 256 + n0] = (short)h0l;
            lds[wH + 256 + n1] = (short)h1l;
        }
        pv0 = nv0; pv1 = nv1;
        nv0 = qv0; nv1 = qv1;
        lds_barrier();
    }
}

extern "C" void kernel_launch(void* const* d_in, const int* in_sizes, int n_in,
                              void* d_out, int out_size, void* d_ws, size_t ws_size,
                              hipStream_t stream)
{
    const int*   ids    = (const int*)  d_in[0];
    const float* emb    = (const float*)d_in[1];
    const float* W_ih0  = (const float*)d_in[2];
    const float* W_hh0  = (const float*)d_in[3];
    const float* b_ih0  = (const float*)d_in[4];
    const float* b_hh0  = (const float*)d_in[5];
    const float* W_ih1  = (const float*)d_in[6];
    const float* W_hh1  = (const float*)d_in[7];
    const float* b_ih1  = (const float*)d_in[8];
    const float* b_hh1  = (const float*)d_in[9];
    const float* W_head = (const float*)d_in[10];

    float* out = (float*)d_out;
    const int M = B_DIM * T_DIM;              // 65536
    float* pre0 = out;                        // [0, 64 MiB)
    float* pre1 = out + (size_t)M * D_DIM;    // [64, 128 MiB)

    // Split tables live in DEAD d_out regions (pre0+pre1 fill d_out exactly):
    //  - emb/W_ih0 planes at start of pre1 region: read by gemm0 (which only
    //    writes pre0), then overwritten by gemm1's pre1 output (dead by then).
    //  - W_ih1 planes at start of pre0 region, split AFTER scan0 consumed
    //    pre0; read by gemm1 (which only writes pre1); head clobbers last.
    unsigned short* embHi = (unsigned short*)pre1;                  // 2 MB
    unsigned short* embLo = embHi + (size_t)4096 * 256;             // 2 MB
    unsigned short* w0Hi  = embLo + (size_t)4096 * 256;             // 128 KB
    unsigned short* w0Lo  = w0Hi + 256 * 256;                       // 128 KB
    unsigned short* w1Hi  = (unsigned short*)pre0;                  // 128 KB
    unsigned short* w1Lo  = w1Hi + 256 * 256;                       // 128 KB

    // ws: h planes (hi 32 MB, lo 32 MB); h1 planes overwritten by h2 planes.
    unsigned short* hHi = (unsigned short*)d_ws;
    unsigned short* hLo = hHi + (size_t)M * D_DIM;

    // prep: split emb + W_ih0 (into pre1 region)
    split_planes<<<dim3(1024), dim3(256), 0, stream>>>(emb, embHi, embLo, 4096 * 256 / 4);
    split_planes<<<dim3(64),   dim3(256), 0, stream>>>(W_ih0, w0Hi, w0Lo, 256 * 256 / 4);
    // pre0 = emb[ids] @ W_ih0^T + (b_ih0 + b_hh0)
    gemm_pp<<<dim3(M / 128, D_DIM / 128), dim3(256), 0, stream>>>(
        embHi, embLo, w0Hi, w0Lo, pre0, b_ih0, b_hh0, ids, M, D_DIM, D_DIM);
    // layer-0 recurrence -> h1 planes (ws)
    rnn_scan_mfma<<<dim3(B_DIM), dim3(512), 0, stream>>>(pre0, W_hh0, hHi, hLo);
    // split W_ih1 into (now dead) pre0 region
    split_planes<<<dim3(64), dim3(256), 0, stream>>>(W_ih1, w1Hi, w1Lo, 256 * 256 / 4);
    // pre1 = h1 @ W_ih1^T + (b_ih1 + b_hh1)
    gemm_pp<<<dim3(M / 128, D_DIM / 128), dim3(256), 0, stream>>>(
        hHi, hLo, w1Hi, w1Lo, pre1, b_ih1, b_hh1, nullptr, M, D_DIM, D_DIM);
    // layer-1 recurrence -> h2 planes (ws, overwrites h1 planes)
    rnn_scan_mfma<<<dim3(B_DIM), dim3(512), 0, stream>>>(pre1, W_hh1, hHi, hLo);
    // logits = h2 @ W_head^T (B split on the fly; clobbers all of d_out last)
    gemm_pf<<<dim3(M / 128, S_DIM / 128), dim3(256), 0, stream>>>(
        hHi, hLo, W_head, out, M, S_DIM, D_DIM);
}

// Round 10
// 839.985 us; speedup vs baseline: 1.3336x; 1.3336x over previous
//
#include <hip/hip_runtime.h>
#include <cstdint>
#include <cstddef>

#define D_DIM 256
#define T_DIM 512
#define B_DIM 128
#define S_DIM 512

typedef __attribute__((ext_vector_type(8))) short short8;
typedef __attribute__((ext_vector_type(4))) float f32x4;

// ---------- helpers ----------
__device__ inline unsigned short f2bf(float x) {
    unsigned u = __builtin_bit_cast(unsigned, x);
    unsigned r = (u + 0x7fffu + ((u >> 16) & 1u)) >> 16;
    return (unsigned short)r;
}
__device__ inline float bf2f(unsigned short b) {
    unsigned u = ((unsigned)b) << 16;
    return __builtin_bit_cast(float, u);
}
__device__ inline float fast_tanh(float x) {
    float ax = __builtin_fabsf(x);
    float e  = __expf(-2.0f * ax);
    float r  = (1.0f - e) * __builtin_amdgcn_rcpf(1.0f + e);
    return __builtin_copysignf(r, x);
}

// Truncation split: x = bf2f(hi) + lo-term; residual exact, lo truncated ->
// total err <= 2^-16 |x|.  Pair-packed: low 16 bits of .x = element 0.
__device__ inline void split4(float4 v, uint2& hi, uint2& lo) {
    unsigned u0 = __builtin_bit_cast(unsigned, v.x);
    unsigned u1 = __builtin_bit_cast(unsigned, v.y);
    unsigned u2 = __builtin_bit_cast(unsigned, v.z);
    unsigned u3 = __builtin_bit_cast(unsigned, v.w);
    hi.x = (u0 >> 16) | (u1 & 0xFFFF0000u);
    hi.y = (u2 >> 16) | (u3 & 0xFFFF0000u);
    float r0 = v.x - __builtin_bit_cast(float, u0 & 0xFFFF0000u);
    float r1 = v.y - __builtin_bit_cast(float, u1 & 0xFFFF0000u);
    float r2 = v.z - __builtin_bit_cast(float, u2 & 0xFFFF0000u);
    float r3 = v.w - __builtin_bit_cast(float, u3 & 0xFFFF0000u);
    lo.x = (__builtin_bit_cast(unsigned, r0) >> 16)
         | (__builtin_bit_cast(unsigned, r1) & 0xFFFF0000u);
    lo.y = (__builtin_bit_cast(unsigned, r2) >> 16)
         | (__builtin_bit_cast(unsigned, r3) & 0xFFFF0000u);
}

// ---------- split-bf16 MFMA GEMM v3 (R7-verified): C = A @ B^T (+biases) ----
// R8 post-mortem: pre-split planes did NOT speed this up -> not staging-VALU
// bound; residual is the 2-phase stage/barrier stall at K=256 (4 BK-iters,
// pipeline never fills).  Keep the verified v3 as-is.
__global__ __launch_bounds__(256, 2)
void gemm_bt_mfma(const float* __restrict__ A, const float* __restrict__ Bm,
                  float* __restrict__ C,
                  const float* __restrict__ bias1, const float* __restrict__ bias2,
                  const int* __restrict__ ids, const float* __restrict__ emb,
                  int M, int N, int K)
{
    // LDS planes (bf16, [128 rows][64 k], row stride 128 B, swizzled):
    // Ahi @0, Alo @16K, Bhi @32K, Blo @48K  -> 64 KB total.
    __shared__ char smem[65536];

    const int tid  = threadIdx.x;
    const int lane = tid & 63;
    const int quad = lane >> 4;
    const int lcol = lane & 15;
    const int wv   = tid >> 6;
    const int wm   = (wv & 1) * 64;    // wave m-offset in tile
    const int wn   = (wv >> 1) * 64;   // wave n-offset in tile
    const int m0   = blockIdx.x * 128;
    const int n0   = blockIdx.y * 128;

    // staging map: thread covers rows rm+16i (i=0..7), float4-col kq.
    const int rm = tid >> 4;           // 0..15
    const int kq = tid & 15;           // 0..15  (float4 within BK=64)

    const float* arowp[8];
    const float* browp[8];
#pragma unroll
    for (int i = 0; i < 8; ++i) {
        int gm = m0 + rm + i * 16;
        arowp[i] = ids ? (emb + (size_t)ids[gm] * K) : (A + (size_t)gm * K);
        browp[i] = Bm + (size_t)(n0 + rm + i * 16) * K;
    }
    // per-thread swizzled LDS write offset (same for all planes)
    int woff[8];
#pragma unroll
    for (int i = 0; i < 8; ++i) {
        int m = rm + i * 16;
        woff[i] = (m * 128 + kq * 8) ^ ((m & 7) << 4);
    }

    f32x4 acc[4][4];
#pragma unroll
    for (int mt = 0; mt < 4; ++mt)
#pragma unroll
        for (int nt = 0; nt < 4; ++nt) acc[mt][nt] = (f32x4){0.f, 0.f, 0.f, 0.f};

    // prologue: prefetch A for iter 0
    float4 pa[8];
#pragma unroll
    for (int i = 0; i < 8; ++i)
        pa[i] = *(const float4*)(arowp[i] + kq * 4);

    for (int it = 0; it < 4; ++it) {
        const int kc = it * 64;
        // issue B loads early (before barrier; LDS untouched by them)
        float4 pb[8];
#pragma unroll
        for (int i = 0; i < 8; ++i)
            pb[i] = *(const float4*)(browp[i] + kc + kq * 4);

        if (it) __syncthreads();       // prior tile's reads complete

#pragma unroll
        for (int i = 0; i < 8; ++i) {
            uint2 hi, lo;
            split4(pa[i], hi, lo);
            *(uint2*)(smem + 0     + woff[i]) = hi;
            *(uint2*)(smem + 16384 + woff[i]) = lo;
        }
#pragma unroll
        for (int i = 0; i < 8; ++i) {
            uint2 hi, lo;
            split4(pb[i], hi, lo);
            *(uint2*)(smem + 32768 + woff[i]) = hi;
            *(uint2*)(smem + 49152 + woff[i]) = lo;
        }
        __syncthreads();

        if (it < 3) {                  // prefetch next A tile under compute
#pragma unroll
            for (int i = 0; i < 8; ++i)
                pa[i] = *(const float4*)(arowp[i] + kc + 64 + kq * 4);
        }

#pragma unroll
        for (int ks = 0; ks < 2; ++ks) {
            short8 aHi[4], aLo[4], bHi[4], bLo[4];
#pragma unroll
            for (int mt = 0; mt < 4; ++mt) {
                int m = wm + mt * 16 + lcol;
                int off = (m * 128 + ks * 64 + quad * 16) ^ ((m & 7) << 4);
                aHi[mt] = *(const short8*)(smem + off);
                aLo[mt] = *(const short8*)(smem + 16384 + off);
            }
#pragma unroll
            for (int nt = 0; nt < 4; ++nt) {
                int n = wn + nt * 16 + lcol;
                int off = (n * 128 + ks * 64 + quad * 16) ^ ((n & 7) << 4);
                bHi[nt] = *(const short8*)(smem + 32768 + off);
                bLo[nt] = *(const short8*)(smem + 49152 + off);
            }
#pragma unroll
            for (int mt = 0; mt < 4; ++mt)
#pragma unroll
                for (int nt = 0; nt < 4; ++nt) {
                    acc[mt][nt] = __builtin_amdgcn_mfma_f32_16x16x32_bf16(aHi[mt], bHi[nt], acc[mt][nt], 0, 0, 0);
                    acc[mt][nt] = __builtin_amdgcn_mfma_f32_16x16x32_bf16(aLo[mt], bHi[nt], acc[mt][nt], 0, 0, 0);
                    acc[mt][nt] = __builtin_amdgcn_mfma_f32_16x16x32_bf16(aHi[mt], bLo[nt], acc[mt][nt], 0, 0, 0);
                }
        }
    }

    // epilogue: D row = quad*4 + reg, col = lcol (per 16x16 fragment)
    float bv[4];
#pragma unroll
    for (int nt = 0; nt < 4; ++nt) {
        int gn = n0 + wn + nt * 16 + lcol;
        float v = 0.f;
        if (bias1) v += bias1[gn];
        if (bias2) v += bias2[gn];
        bv[nt] = v;
    }
#pragma unroll
    for (int mt = 0; mt < 4; ++mt) {
        int gmb = m0 + wm + mt * 16 + quad * 4;
#pragma unroll
        for (int r = 0; r < 4; ++r) {
            float* crow = C + (size_t)(gmb + r) * N + n0 + wn;
#pragma unroll
            for (int nt = 0; nt < 4; ++nt)
                crow[nt * 16 + lcol] = acc[mt][nt][r] + bv[nt];
        }
    }
}

// LDS-only barrier (R1: neutral vs __syncthreads; kept, documents intent).
__device__ inline void lds_barrier() {
    asm volatile("s_waitcnt lgkmcnt(0)" ::: "memory");
    __builtin_amdgcn_s_barrier();
    __builtin_amdgcn_sched_barrier(0);
}

// ---------- MFMA Elman scan v2: hh+lh only (hl pass dropped) ----------
// R8 analysis: of the 32 MFMA/wave/step, 16 were the B=wl (hl) pass.
// h_hi in A-row 0 / h_lo in A-row 1 with B=wh gives hh (C reg[0]) and
// lh (C reg[1]) in ONE pass -- lh is free.  Dropping hl halves the MFMA
// issue floor (1242 -> 621 cyc/step).  Numerics: hl = h_hi*W_lo,
// |W_lo| <= 2^-9|W|; pre-act err sigma ~3e-4, recurrence gain <1 ->
// expected absmax ~2e-3..8e-3 (was 1e-3).  Calculated risk vs tolerance.
__global__ __launch_bounds__(512) __attribute__((amdgpu_waves_per_eu(2, 2)))
void rnn_scan_mfma(const float* __restrict__ pre, const float* __restrict__ Whh,
                   float* __restrict__ hout)
{
    const int tid  = threadIdx.x;
    const int wave = tid >> 6;
    const int lane = tid & 63;
    const int quad = lane >> 4;
    const int lcol = lane & 15;
    const int b    = blockIdx.x;

    // LDS layout (shorts): Hh[0]@0, Hl[0]@256, Hh[1]@512, Hl[1]@768.
    __shared__ short lds[1024];
    for (int i = tid; i < 1024; i += 512) lds[i] = 0;

    // --- W_hh hi fragments only: B-operand layout, lane holds W[n, k] ---
    short8 wh[2][8];
#pragma unroll
    for (int tile = 0; tile < 2; ++tile) {
        const int n = wave * 32 + tile * 16 + lcol;
        const float* wr = Whh + (size_t)n * D_DIM + quad * 8;
#pragma unroll
        for (int kt = 0; kt < 8; ++kt) {
            float4 x0 = *(const float4*)(wr + kt * 32);
            float4 x1 = *(const float4*)(wr + kt * 32 + 4);
            float xs[8] = {x0.x, x0.y, x0.z, x0.w, x1.x, x1.y, x1.z, x1.w};
            short8 hi8;
#pragma unroll
            for (int j = 0; j < 8; ++j) hi8[j] = (short)f2bf(xs[j]);
            wh[tile][kt] = hi8;
        }
    }

    const bool active = (lane < 16);           // quad==0 holds C rows 0..3
    const int n0 = wave * 32 + lcol;           // tile 0 unit
    const int n1 = n0 + 16;                    // tile 1 unit
    const size_t rowbase = (size_t)b * T_DIM * D_DIM;

    // Persistent packed A fragment: row 0 (lanes lcol==0) = h_hi chunk,
    // row 1 (lanes lcol==1) = h_lo chunk, rows 2..15 permanently zero.
    const short8 ZS = {0, 0, 0, 0, 0, 0, 0, 0};
    short8 aP[8];
#pragma unroll
    for (int kt = 0; kt < 8; ++kt) aP[kt] = ZS;

    const int aq = quad * 8;                   // k-chunk within buffer

    // 2-step-deep pre pipeline: pv = step t, nv = step t+1
    float pv0 = 0.f, pv1 = 0.f, nv0 = 0.f, nv1 = 0.f;
    if (active) {
        pv0 = pre[rowbase + n0];
        pv1 = pre[rowbase + n1];
        nv0 = pre[rowbase + D_DIM + n0];
        nv1 = pre[rowbase + D_DIM + n1];
    }
    lds_barrier();

    const f32x4 Z = {0.f, 0.f, 0.f, 0.f};

    for (int t = 0; t < T_DIM; ++t) {
        // prefetch step t+2's pre
        float qv0 = 0.f, qv1 = 0.f;
        if (active && t + 2 < T_DIM) {
            const float* p2 = pre + rowbase + (size_t)(t + 2) * D_DIM;
            qv0 = p2[n0];
            qv1 = p2[n1];
        }

        // exec-masked A loads: lanes lcol==0 read h_hi, lcol==1 read h_lo
        const int bh = (t & 1) ? 512 : 0;
        if (lcol < 2) {
            const short* pa = lds + bh + lcol * 256 + aq;
#pragma unroll
            for (int kt = 0; kt < 8; ++kt)
                aP[kt] = *(const short8*)(pa + kt * 32);
        }

        // 2 chains: B=wh, row0=hh, row1=lh (lh rides free in the same MFMA)
        f32x4 a1t0, a1t1;
        a1t0 = __builtin_amdgcn_mfma_f32_16x16x32_bf16(aP[0], wh[0][0], Z, 0, 0, 0);
        a1t1 = __builtin_amdgcn_mfma_f32_16x16x32_bf16(aP[0], wh[1][0], Z, 0, 0, 0);
#pragma unroll
        for (int kt = 1; kt < 8; ++kt) {
            a1t0 = __builtin_amdgcn_mfma_f32_16x16x32_bf16(aP[kt], wh[0][kt], a1t0, 0, 0, 0);
            a1t1 = __builtin_amdgcn_mfma_f32_16x16x32_bf16(aP[kt], wh[1][kt], a1t1, 0, 0, 0);
        }

        // epilogue: lanes 0..15 hold C rows 0 (reg 0: hh) and 1 (reg 1: lh)
        if (active) {
            const int wH = (t & 1) ? 0 : 512;   // write the other buffer
            float x0 = a1t0[0] + a1t0[1] + pv0;
            float x1 = a1t1[0] + a1t1[1] + pv1;
            float h0 = fast_tanh(x0);
            float h1 = fast_tanh(x1);
            hout[rowbase + (size_t)t * D_DIM + n0] = h0;   // stays in flight
            hout[rowbase + (size_t)t * D_DIM + n1] = h1;
            unsigned short h0h = f2bf(h0);
            unsigned short h0l = f2bf(h0 - bf2f(h0h));
            unsigned short h1h = f2bf(h1);
            unsigned short h1l = f2bf(h1 - bf2f(h1h));
            lds[wH + n0]       = (short)h0h;
            lds[wH + n1]       = (short)h1h;
            lds[wH + 256 + n0] = (short)h0l;
            lds[wH + 256 + n1] = (short)h1l;
        }
        pv0 = nv0; pv1 = nv1;
        nv0 = qv0; nv1 = qv1;
        lds_barrier();
    }
}

extern "C" void kernel_launch(void* const* d_in, const int* in_sizes, int n_in,
                              void* d_out, int out_size, void* d_ws, size_t ws_size,
                              hipStream_t stream)
{
    const int*   ids    = (const int*)  d_in[0];
    const float* emb    = (const float*)d_in[1];
    const float* W_ih0  = (const float*)d_in[2];
    const float* W_hh0  = (const float*)d_in[3];
    const float* b_ih0  = (const float*)d_in[4];
    const float* b_hh0  = (const float*)d_in[5];
    const float* W_ih1  = (const float*)d_in[6];
    const float* W_hh1  = (const float*)d_in[7];
    const float* b_ih1  = (const float*)d_in[8];
    const float* b_hh1  = (const float*)d_in[9];
    const float* W_head = (const float*)d_in[10];

    float* out = (float*)d_out;
    const int M = B_DIM * T_DIM;              // 65536
    float* pre0 = out;                        // d_out doubles as scratch
    float* pre1 = out + (size_t)M * D_DIM;
    float* h1   = (float*)d_ws;               // 64 MB of ws
    float* h2   = h1;

    // pre0 = emb[ids] @ W_ih0^T + (b_ih0 + b_hh0)
    gemm_bt_mfma<<<dim3(M / 128, D_DIM / 128), dim3(256), 0, stream>>>(
        nullptr, W_ih0, pre0, b_ih0, b_hh0, ids, emb, M, D_DIM, D_DIM);
    // layer-0 recurrence (MFMA, A-row-packed, hh+lh only)
    rnn_scan_mfma<<<dim3(B_DIM), dim3(512), 0, stream>>>(pre0, W_hh0, h1);
    // pre1 = h1 @ W_ih1^T + (b_ih1 + b_hh1)
    gemm_bt_mfma<<<dim3(M / 128, D_DIM / 128), dim3(256), 0, stream>>>(
        h1, W_ih1, pre1, b_ih1, b_hh1, nullptr, nullptr, M, D_DIM, D_DIM);
    // layer-1 recurrence
    rnn_scan_mfma<<<dim3(B_DIM), dim3(512), 0, stream>>>(pre1, W_hh1, h2);
    // logits = h2 @ W_head^T
    gemm_bt_mfma<<<dim3(M / 128, S_DIM / 128), dim3(256), 0, stream>>>(
        h2, W_head, out, nullptr, nullptr, nullptr, nullptr, M, S_DIM, D_DIM);
}

// Round 11
// 831.676 us; speedup vs baseline: 1.3469x; 1.0100x over previous
//
#include <hip/hip_runtime.h>
#include <cstdint>
#include <cstddef>

#define D_DIM 256
#define T_DIM 512
#define B_DIM 128
#define S_DIM 512

typedef __attribute__((ext_vector_type(8))) short short8;
typedef __attribute__((ext_vector_type(4))) float f32x4;

// ---------- helpers ----------
__device__ inline unsigned short f2bf(float x) {
    unsigned u = __builtin_bit_cast(unsigned, x);
    unsigned r = (u + 0x7fffu + ((u >> 16) & 1u)) >> 16;
    return (unsigned short)r;
}
__device__ inline float bf2f(unsigned short b) {
    unsigned u = ((unsigned)b) << 16;
    return __builtin_bit_cast(float, u);
}
__device__ inline float fast_tanh(float x) {
    float ax = __builtin_fabsf(x);
    float e  = __expf(-2.0f * ax);
    float r  = (1.0f - e) * __builtin_amdgcn_rcpf(1.0f + e);
    return __builtin_copysignf(r, x);
}

// Truncation split: x = bf2f(hi) + lo-term; residual exact, lo truncated ->
// total err <= 2^-16 |x|.  Pair-packed: low 16 bits of .x = element 0.
__device__ inline void split4(float4 v, uint2& hi, uint2& lo) {
    unsigned u0 = __builtin_bit_cast(unsigned, v.x);
    unsigned u1 = __builtin_bit_cast(unsigned, v.y);
    unsigned u2 = __builtin_bit_cast(unsigned, v.z);
    unsigned u3 = __builtin_bit_cast(unsigned, v.w);
    hi.x = (u0 >> 16) | (u1 & 0xFFFF0000u);
    hi.y = (u2 >> 16) | (u3 & 0xFFFF0000u);
    float r0 = v.x - __builtin_bit_cast(float, u0 & 0xFFFF0000u);
    float r1 = v.y - __builtin_bit_cast(float, u1 & 0xFFFF0000u);
    float r2 = v.z - __builtin_bit_cast(float, u2 & 0xFFFF0000u);
    float r3 = v.w - __builtin_bit_cast(float, u3 & 0xFFFF0000u);
    lo.x = (__builtin_bit_cast(unsigned, r0) >> 16)
         | (__builtin_bit_cast(unsigned, r1) & 0xFFFF0000u);
    lo.y = (__builtin_bit_cast(unsigned, r2) >> 16)
         | (__builtin_bit_cast(unsigned, r3) & 0xFFFF0000u);
}

// ---------- split-bf16 MFMA GEMM v4: BK=32, 32KB LDS, 3 blocks/CU ----------
// R10 analysis: GEMMs at ~5x MFMA floor; R8 ruled out staging VALU.  64KB
// LDS + (256,2) capped occupancy at 2 blocks/CU -> barrier stalls exposed.
// v4: BK=32 halves LDS to 32KB, launch_bounds(256,3) -> 3 blocks/CU, 8
// K-iters.  64B LDS rows need new swizzle: off = m*64 + ((s*16) ^
// (((m>>1)&3)<<4)) -> fragment reads <=2-way (free) bank aliasing; write
// side uses the same involution.  Products hh+lh+hl as verified (R5/R7).
__global__ __launch_bounds__(256, 3)
void gemm_bt_mfma(const float* __restrict__ A, const float* __restrict__ Bm,
                  float* __restrict__ C,
                  const float* __restrict__ bias1, const float* __restrict__ bias2,
                  const int* __restrict__ ids, const float* __restrict__ emb,
                  int M, int N, int K)
{
    // planes (bf16 [128 rows][32 k], row = 64B): Ahi@0 Alo@8K Bhi@16K Blo@24K
    __shared__ char smem[32768];

    const int tid  = threadIdx.x;
    const int lane = tid & 63;
    const int quad = lane >> 4;
    const int lcol = lane & 15;
    const int wv   = tid >> 6;
    const int wm   = (wv & 1) * 64;
    const int wn   = (wv >> 1) * 64;
    const int m0   = blockIdx.x * 128;
    const int n0   = blockIdx.y * 128;

    // staging map: thread t -> row rs = t>>1, k-half hh = t&1 (k hh*16..+15)
    const int rs = tid >> 1;
    const int hf = tid & 1;
    const int gmA = m0 + rs;
    const float* arow = (ids ? (emb + (size_t)ids[gmA] * K)
                             : (A + (size_t)gmA * K)) + hf * 16;
    const float* brow = Bm + (size_t)(n0 + rs) * K + hf * 16;

    // swizzled 16B-slot write offsets (slots s=2hf, 2hf+1; same XOR per row)
    const int swz = ((rs >> 1) & 3) << 4;
    const int ws0 = rs * 64 + (((hf * 2)     << 4) ^ swz);
    const int ws1 = rs * 64 + (((hf * 2 + 1) << 4) ^ swz);

    f32x4 acc[4][4];
#pragma unroll
    for (int mt = 0; mt < 4; ++mt)
#pragma unroll
        for (int nt = 0; nt < 4; ++nt) acc[mt][nt] = (f32x4){0.f, 0.f, 0.f, 0.f};

    // prologue: prefetch A for iter 0 (4 float4 = k hf*16..hf*16+15)
    float4 pa0 = *(const float4*)(arow + 0);
    float4 pa1 = *(const float4*)(arow + 4);
    float4 pa2 = *(const float4*)(arow + 8);
    float4 pa3 = *(const float4*)(arow + 12);

    for (int it = 0; it < 8; ++it) {
        const int kc = it * 32;
        // B loads issued early (LDS untouched by them)
        float4 pb0 = *(const float4*)(brow + kc + 0);
        float4 pb1 = *(const float4*)(brow + kc + 4);
        float4 pb2 = *(const float4*)(brow + kc + 8);
        float4 pb3 = *(const float4*)(brow + kc + 12);

        if (it) __syncthreads();       // prior iter's fragment reads complete

        {   // A planes
            uint2 h0, l0, h1, l1, h2, l2, h3, l3;
            split4(pa0, h0, l0); split4(pa1, h1, l1);
            split4(pa2, h2, l2); split4(pa3, h3, l3);
            *(uint4*)(smem + 0    + ws0) = make_uint4(h0.x, h0.y, h1.x, h1.y);
            *(uint4*)(smem + 0    + ws1) = make_uint4(h2.x, h2.y, h3.x, h3.y);
            *(uint4*)(smem + 8192 + ws0) = make_uint4(l0.x, l0.y, l1.x, l1.y);
            *(uint4*)(smem + 8192 + ws1) = make_uint4(l2.x, l2.y, l3.x, l3.y);
        }
        {   // B planes
            uint2 h0, l0, h1, l1, h2, l2, h3, l3;
            split4(pb0, h0, l0); split4(pb1, h1, l1);
            split4(pb2, h2, l2); split4(pb3, h3, l3);
            *(uint4*)(smem + 16384 + ws0) = make_uint4(h0.x, h0.y, h1.x, h1.y);
            *(uint4*)(smem + 16384 + ws1) = make_uint4(h2.x, h2.y, h3.x, h3.y);
            *(uint4*)(smem + 24576 + ws0) = make_uint4(l0.x, l0.y, l1.x, l1.y);
            *(uint4*)(smem + 24576 + ws1) = make_uint4(l2.x, l2.y, l3.x, l3.y);
        }
        __syncthreads();

        if (it < 7) {                  // prefetch next A under compute
            pa0 = *(const float4*)(arow + kc + 32);
            pa1 = *(const float4*)(arow + kc + 36);
            pa2 = *(const float4*)(arow + kc + 40);
            pa3 = *(const float4*)(arow + kc + 44);
        }

        short8 aHi[4], aLo[4], bHi[4], bLo[4];
#pragma unroll
        for (int mt = 0; mt < 4; ++mt) {
            int m = wm + mt * 16 + lcol;
            int off = m * 64 + ((quad * 16) ^ ((((m >> 1) & 3)) << 4));
            aHi[mt] = *(const short8*)(smem + off);
            aLo[mt] = *(const short8*)(smem + 8192 + off);
        }
#pragma unroll
        for (int nt = 0; nt < 4; ++nt) {
            int n = wn + nt * 16 + lcol;
            int off = n * 64 + ((quad * 16) ^ ((((n >> 1) & 3)) << 4));
            bHi[nt] = *(const short8*)(smem + 16384 + off);
            bLo[nt] = *(const short8*)(smem + 24576 + off);
        }
#pragma unroll
        for (int mt = 0; mt < 4; ++mt)
#pragma unroll
            for (int nt = 0; nt < 4; ++nt) {
                acc[mt][nt] = __builtin_amdgcn_mfma_f32_16x16x32_bf16(aHi[mt], bHi[nt], acc[mt][nt], 0, 0, 0);
                acc[mt][nt] = __builtin_amdgcn_mfma_f32_16x16x32_bf16(aLo[mt], bHi[nt], acc[mt][nt], 0, 0, 0);
                acc[mt][nt] = __builtin_amdgcn_mfma_f32_16x16x32_bf16(aHi[mt], bLo[nt], acc[mt][nt], 0, 0, 0);
            }
    }

    // epilogue: D row = quad*4 + reg, col = lcol (per 16x16 fragment)
    float bv[4];
#pragma unroll
    for (int nt = 0; nt < 4; ++nt) {
        int gn = n0 + wn + nt * 16 + lcol;
        float v = 0.f;
        if (bias1) v += bias1[gn];
        if (bias2) v += bias2[gn];
        bv[nt] = v;
    }
#pragma unroll
    for (int mt = 0; mt < 4; ++mt) {
        int gmb = m0 + wm + mt * 16 + quad * 4;
#pragma unroll
        for (int r = 0; r < 4; ++r) {
            float* crow = C + (size_t)(gmb + r) * N + n0 + wn;
#pragma unroll
            for (int nt = 0; nt < 4; ++nt)
                crow[nt * 16 + lcol] = acc[mt][nt][r] + bv[nt];
        }
    }
}

// LDS-only barrier (R1: neutral vs __syncthreads; kept, documents intent).
__device__ inline void lds_barrier() {
    asm volatile("s_waitcnt lgkmcnt(0)" ::: "memory");
    __builtin_amdgcn_s_barrier();
    __builtin_amdgcn_sched_barrier(0);
}

// ---------- MFMA Elman scan v3: hh+lh, chain-split 2x4 ----------
// R10: scan is AT its MFMA issue floor (128 MFMA/CU/step = 621 cyc; step
// 1356).  Residual ~735 cyc serial: ds_read ~160 + 8-deep dependent MFMA
// chain ~160 + tanh ~70 + pack/barrier.  v3 splits each 8-deep chain into
// two independent 4-chains (halves chain latency; fp32-add reorder only).
__global__ __launch_bounds__(512) __attribute__((amdgpu_waves_per_eu(2, 2)))
void rnn_scan_mfma(const float* __restrict__ pre, const float* __restrict__ Whh,
                   float* __restrict__ hout)
{
    const int tid  = threadIdx.x;
    const int wave = tid >> 6;
    const int lane = tid & 63;
    const int quad = lane >> 4;
    const int lcol = lane & 15;
    const int b    = blockIdx.x;

    // LDS layout (shorts): Hh[0]@0, Hl[0]@256, Hh[1]@512, Hl[1]@768.
    __shared__ short lds[1024];
    for (int i = tid; i < 1024; i += 512) lds[i] = 0;

    // --- W_hh hi fragments only: B-operand layout, lane holds W[n, k] ---
    short8 wh[2][8];
#pragma unroll
    for (int tile = 0; tile < 2; ++tile) {
        const int n = wave * 32 + tile * 16 + lcol;
        const float* wr = Whh + (size_t)n * D_DIM + quad * 8;
#pragma unroll
        for (int kt = 0; kt < 8; ++kt) {
            float4 x0 = *(const float4*)(wr + kt * 32);
            float4 x1 = *(const float4*)(wr + kt * 32 + 4);
            float xs[8] = {x0.x, x0.y, x0.z, x0.w, x1.x, x1.y, x1.z, x1.w};
            short8 hi8;
#pragma unroll
            for (int j = 0; j < 8; ++j) hi8[j] = (short)f2bf(xs[j]);
            wh[tile][kt] = hi8;
        }
    }

    const bool active = (lane < 16);           // quad==0 holds C rows 0..3
    const int n0 = wave * 32 + lcol;           // tile 0 unit
    const int n1 = n0 + 16;                    // tile 1 unit
    const size_t rowbase = (size_t)b * T_DIM * D_DIM;

    // Persistent packed A fragment: row 0 (lanes lcol==0) = h_hi chunk,
    // row 1 (lanes lcol==1) = h_lo chunk, rows 2..15 permanently zero.
    const short8 ZS = {0, 0, 0, 0, 0, 0, 0, 0};
    short8 aP[8];
#pragma unroll
    for (int kt = 0; kt < 8; ++kt) aP[kt] = ZS;

    const int aq = quad * 8;                   // k-chunk within buffer

    // 2-step-deep pre pipeline: pv = step t, nv = step t+1
    float pv0 = 0.f, pv1 = 0.f, nv0 = 0.f, nv1 = 0.f;
    if (active) {
        pv0 = pre[rowbase + n0];
        pv1 = pre[rowbase + n1];
        nv0 = pre[rowbase + D_DIM + n0];
        nv1 = pre[rowbase + D_DIM + n1];
    }
    lds_barrier();

    const f32x4 Z = {0.f, 0.f, 0.f, 0.f};

    for (int t = 0; t < T_DIM; ++t) {
        // prefetch step t+2's pre
        float qv0 = 0.f, qv1 = 0.f;
        if (active && t + 2 < T_DIM) {
            const float* p2 = pre + rowbase + (size_t)(t + 2) * D_DIM;
            qv0 = p2[n0];
            qv1 = p2[n1];
        }

        // exec-masked A loads: lanes lcol==0 read h_hi, lcol==1 read h_lo
        const int bh = (t & 1) ? 512 : 0;
        if (lcol < 2) {
            const short* pa = lds + bh + lcol * 256 + aq;
#pragma unroll
            for (int kt = 0; kt < 8; ++kt)
                aP[kt] = *(const short8*)(pa + kt * 32);
        }

        // 4 independent 4-deep chains (2 per tile): halves dep-chain latency
        f32x4 c0t0, c1t0, c0t1, c1t1;
        c0t0 = __builtin_amdgcn_mfma_f32_16x16x32_bf16(aP[0], wh[0][0], Z, 0, 0, 0);
        c0t1 = __builtin_amdgcn_mfma_f32_16x16x32_bf16(aP[0], wh[1][0], Z, 0, 0, 0);
        c1t0 = __builtin_amdgcn_mfma_f32_16x16x32_bf16(aP[4], wh[0][4], Z, 0, 0, 0);
        c1t1 = __builtin_amdgcn_mfma_f32_16x16x32_bf16(aP[4], wh[1][4], Z, 0, 0, 0);
#pragma unroll
        for (int kt = 1; kt < 4; ++kt) {
            c0t0 = __builtin_amdgcn_mfma_f32_16x16x32_bf16(aP[kt],     wh[0][kt],     c0t0, 0, 0, 0);
            c0t1 = __builtin_amdgcn_mfma_f32_16x16x32_bf16(aP[kt],     wh[1][kt],     c0t1, 0, 0, 0);
            c1t0 = __builtin_amdgcn_mfma_f32_16x16x32_bf16(aP[kt + 4], wh[0][kt + 4], c1t0, 0, 0, 0);
            c1t1 = __builtin_amdgcn_mfma_f32_16x16x32_bf16(aP[kt + 4], wh[1][kt + 4], c1t1, 0, 0, 0);
        }

        // epilogue: lanes 0..15 hold C rows 0 (reg 0: hh) and 1 (reg 1: lh)
        if (active) {
            const int wH = (t & 1) ? 0 : 512;   // write the other buffer
            float x0 = (c0t0[0] + c1t0[0]) + (c0t0[1] + c1t0[1]) + pv0;
            float x1 = (c0t1[0] + c1t1[0]) + (c0t1[1] + c1t1[1]) + pv1;
            float h0 = fast_tanh(x0);
            float h1 = fast_tanh(x1);
            unsigned short h0h = f2bf(h0);
            unsigned short h0l = f2bf(h0 - bf2f(h0h));
            unsigned short h1h = f2bf(h1);
            unsigned short h1l = f2bf(h1 - bf2f(h1h));
            lds[wH + n0]       = (short)h0h;
            lds[wH + n1]       = (short)h1h;
            lds[wH + 256 + n0] = (short)h0l;
            lds[wH + 256 + n1] = (short)h1l;
            hout[rowbase + (size_t)t * D_DIM + n0] = h0;   // stays in flight
            hout[rowbase + (size_t)t * D_DIM + n1] = h1;
        }
        pv0 = nv0; pv1 = nv1;
        nv0 = qv0; nv1 = qv1;
        lds_barrier();
    }
}

extern "C" void kernel_launch(void* const* d_in, const int* in_sizes, int n_in,
                              void* d_out, int out_size, void* d_ws, size_t ws_size,
                              hipStream_t stream)
{
    const int*   ids    = (const int*)  d_in[0];
    const float* emb    = (const float*)d_in[1];
    const float* W_ih0  = (const float*)d_in[2];
    const float* W_hh0  = (const float*)d_in[3];
    const float* b_ih0  = (const float*)d_in[4];
    const float* b_hh0  = (const float*)d_in[5];
    const float* W_ih1  = (const float*)d_in[6];
    const float* W_hh1  = (const float*)d_in[7];
    const float* b_ih1  = (const float*)d_in[8];
    const float* b_hh1  = (const float*)d_in[9];
    const float* W_head = (const float*)d_in[10];

    float* out = (float*)d_out;
    const int M = B_DIM * T_DIM;              // 65536
    float* pre0 = out;                        // d_out doubles as scratch
    float* pre1 = out + (size_t)M * D_DIM;
    float* h1   = (float*)d_ws;               // 64 MB of ws
    float* h2   = h1;

    // pre0 = emb[ids] @ W_ih0^T + (b_ih0 + b_hh0)
    gemm_bt_mfma<<<dim3(M / 128, D_DIM / 128), dim3(256), 0, stream>>>(
        nullptr, W_ih0, pre0, b_ih0, b_hh0, ids, emb, M, D_DIM, D_DIM);
    // layer-0 recurrence (MFMA, A-row-packed, hh+lh, chain-split)
    rnn_scan_mfma<<<dim3(B_DIM), dim3(512), 0, stream>>>(pre0, W_hh0, h1);
    // pre1 = h1 @ W_ih1^T + (b_ih1 + b_hh1)
    gemm_bt_mfma<<<dim3(M / 128, D_DIM / 128), dim3(256), 0, stream>>>(
        h1, W_ih1, pre1, b_ih1, b_hh1, nullptr, nullptr, M, D_DIM, D_DIM);
    // layer-1 recurrence
    rnn_scan_mfma<<<dim3(B_DIM), dim3(512), 0, stream>>>(pre1, W_hh1, h2);
    // logits = h2 @ W_head^T
    gemm_bt_mfma<<<dim3(M / 128, S_DIM / 128), dim3(256), 0, stream>>>(
        h2, W_head, out, nullptr, nullptr, nullptr, nullptr, M, S_DIM, D_DIM);
}